// Round 4
// baseline (688.825 us; speedup 1.0000x reference)
//
#include <hip/hip_runtime.h>

typedef _Float16 h4 __attribute__((ext_vector_type(4)));
typedef float    f4 __attribute__((ext_vector_type(4)));

// K=16 MFMA: B-frag = T-form h4 DIRECTLY (B[k=4q+i][col=m], k-tile=nt).
// This removes every bfrag shuffle chain (R3 lesson: 1.8e7 bank-conflict
// cycles were ds_bpermute traffic, and VGPR=84 capped occupancy, not LDS).
#define MFMA4(a,b,c) __builtin_amdgcn_mfma_f32_16x16x16f16((a),(b),(c),0,0,0)

#define NSEQ  5200
#define NNODE 325
#define LE    96
#define LD    144
#define OUTL  48
#define NTHR  192   // 3 waves; wave w owns enc tiles w and w+3, dec tile w
                    // (dual-tile = 2 independent chains/wave: ILP is load-bearing)

// XOR-swizzled LDS layouts (no pad):
//  K : 96 rows x 64 halves.  off = r*64 + (c ^ ((r&7)<<3)); XOR hits bits>=3,
//      so 4-aligned h4 runs stay contiguous.
//  Vt: 64 rows x 96 halves.  off = d*96 + (c ^ ((d&3)<<3)).
#define SXE   64
#define SVT   96

#define K_OFF    0
#define VT_OFF   6144
#define MISC_OFF 12288            // 244 floats: serE 96 + serD 144 + stat 4
#define LDS_HALVES 12776          // 25,552 B

// ws layout (halves): 10 transposed 64x64 + dc1t[256][64] + dc2t[64][256]
#define WSQ(i)   ((i)*4096)
#define WS_DC1   40960
#define WS_DC2   57344
#define WS_TOTAL 73728

struct Params {
  const float* x_enc; const float* x_dec;
  const float* enc_conv_w; const float* dec_conv_w;
  const float* eWq; const float* ebq; const float* eWk; const float* ebk;
  const float* eWv; const float* ebv; const float* eWo; const float* ebo;
  const float* ec1_w; const float* ec1_b; const float* ec2_w; const float* ec2_b;
  const float* en1_g; const float* en1_b; const float* en2_g; const float* en2_b;
  const float* dWq; const float* dbq; const float* dWk; const float* dbk;
  const float* dWv; const float* dbv; const float* dWo; const float* dbo;
  const float* dc1_w; const float* dc1_b; const float* dc2_w; const float* dc2_b;
  const float* dn2_g; const float* dn2_b; const float* dn3_g; const float* dn3_b;
  const float* proj_w; const float* proj_b;
  float* out;
};

__device__ __forceinline__ float wave_sum(float v){
  v += __shfl_xor(v, 32, 64); v += __shfl_xor(v, 16, 64);
  v += __shfl_xor(v,  8, 64); v += __shfl_xor(v,  4, 64);
  v += __shfl_xor(v,  2, 64); v += __shfl_xor(v,  1, 64);
  return v;
}
__device__ __forceinline__ float q_sum(float v){
  v += __shfl_xor(v, 16, 64); v += __shfl_xor(v, 32, 64); return v;
}

// dual-tile: Y^T = A @ t for two T-form inputs, sharing the A loads.
// A-frag (16x16x16): lane holds A[row=m][k=kt*16+4q+i] -> h4 global load.
__device__ __forceinline__ void mm64T2(const _Float16* __restrict__ A, int lda,
                                       const h4 ta[4], const h4 tb[4],
                                       f4 oa[4], f4 ob[4], int q, int m){
  #pragma unroll
  for (int nt = 0; nt < 4; ++nt){
    const _Float16* ar = A + (nt*16+m)*lda + 4*q;
    f4 ca = {0.f,0.f,0.f,0.f};
    f4 cb = {0.f,0.f,0.f,0.f};
    #pragma unroll
    for (int kt = 0; kt < 4; ++kt){
      h4 a = *(const h4*)(ar + kt*16);
      ca = MFMA4(a, ta[kt], ca);
      cb = MFMA4(a, tb[kt], cb);
    }
    oa[nt] = ca; ob[nt] = cb;
  }
}
// single-tile variant (decoder)
__device__ __forceinline__ void mm64T(const _Float16* __restrict__ A, int lda,
                                      const h4 t[4], f4 out[4], int q, int m){
  #pragma unroll
  for (int nt = 0; nt < 4; ++nt){
    const _Float16* ar = A + (nt*16+m)*lda + 4*q;
    f4 c = {0.f,0.f,0.f,0.f};
    #pragma unroll
    for (int kt = 0; kt < 4; ++kt){
      h4 a = *(const h4*)(ar + kt*16);
      c = MFMA4(a, t[kt], c);
    }
    out[nt] = c;
  }
}

// LN over d (lane-local 16 + cross-q) -> updates xt
__device__ __forceinline__ void lnT(const f4 vf[4], h4 xt[4],
        const float* __restrict__ g_, const float* __restrict__ b_, int q){
  const int d0 = 4*q;
  float s = 0.f;
  #pragma unroll
  for (int nt = 0; nt < 4; ++nt) s += vf[nt][0]+vf[nt][1]+vf[nt][2]+vf[nt][3];
  s = q_sum(s);
  float mu = s * (1.f/64.f);
  float ss = 0.f;
  #pragma unroll
  for (int nt = 0; nt < 4; ++nt)
    #pragma unroll
    for (int i = 0; i < 4; ++i){ float d = vf[nt][i]-mu; ss += d*d; }
  ss = q_sum(ss);
  float rs = rsqrtf(ss * (1.f/64.f) + 1e-5f);
  #pragma unroll
  for (int nt = 0; nt < 4; ++nt){
    f4 g4 = *(const f4*)(g_ + nt*16 + d0);
    f4 b4 = *(const f4*)(b_ + nt*16 + d0);
    h4 o;
    #pragma unroll
    for (int i = 0; i < 4; ++i) o[i] = (_Float16)((vf[nt][i]-mu)*rs*g4[i] + b4[i]);
    xt[nt] = o;
  }
}

// per-tile scores (K=16, qt[kt] used directly as B-frag) + max-free softmax
// (Wq pre-scaled by 0.125; magnitudes O(0.3) -> exp safe, validated R9).
__device__ __forceinline__ void scoresT(const h4 qt[4], const _Float16* Kb,
                                        h4 pt[6], int q, int m){
  const int swk = (m & 7) << 3;
  f4 s[6];
  #pragma unroll
  for (int st = 0; st < 6; ++st){
    const _Float16* kr = Kb + (st*16+m)*SXE;
    f4 cc = {0.f,0.f,0.f,0.f};
    #pragma unroll
    for (int kt = 0; kt < 4; ++kt){
      h4 a = *(const h4*)(kr + ((kt*16 + 4*q) ^ swk));
      cc = MFMA4(a, qt[kt], cc);
    }
    s[st] = cc;
  }
  float sm = 0.f;
  #pragma unroll
  for (int st = 0; st < 6; ++st)
    #pragma unroll
    for (int i = 0; i < 4; ++i){ float e = __expf(s[st][i]); s[st][i] = e; sm += e; }
  sm = q_sum(sm);
  float r = 1.f/sm;
  #pragma unroll
  for (int st = 0; st < 6; ++st){
    h4 o;
    #pragma unroll
    for (int i = 0; i < 4; ++i) o[i] = (_Float16)(s[st][i]*r);
    pt[st] = o;
  }
}

// dual-tile attention + residual + LN (Wqt pre-scaled by 0.125).
// PV: pt[st] IS the B-frag (k-tile = st over the 96 kv rows).
__device__ __forceinline__ void attnT2(h4 xA[4], h4 xB[4],
        const _Float16* K, const _Float16* Vt,
        const _Float16* __restrict__ Wqt, const float* __restrict__ bq,
        const _Float16* __restrict__ Wot, const float* __restrict__ bo,
        const float* __restrict__ g_, const float* __restrict__ b_, int q, int m){
  const int d0 = 4*q;
  f4 cA[4], cB[4];
  mm64T2(Wqt, 64, xA, xB, cA, cB, q, m);
  h4 qA[4], qB[4];
  #pragma unroll
  for (int nt = 0; nt < 4; ++nt){
    f4 b4 = *(const f4*)(bq + nt*16 + d0);
    h4 oA, oB;
    #pragma unroll
    for (int i = 0; i < 4; ++i){
      oA[i] = (_Float16)(cA[nt][i] + b4[i]*0.125f);
      oB[i] = (_Float16)(cB[nt][i] + b4[i]*0.125f);
    }
    qA[nt] = oA; qB[nt] = oB;
  }
  // S-phase split per tile (liveness control, R8-verified)
  h4 pA[6], pB[6];
  scoresT(qA, K, pA, q, m);
  scoresT(qB, K, pB, q, m);
  // Prefetch Wo A-frags: global latency hides across PV
  h4 wo[4][4];
  #pragma unroll
  for (int nt = 0; nt < 4; ++nt)
    #pragma unroll
    for (int kt = 0; kt < 4; ++kt)
      wo[nt][kt] = *(const h4*)(Wot + (nt*16+m)*64 + kt*16 + 4*q);
  // O^T = V^T @ P^T, shared V loads
  const int swv = (m & 3) << 3;
  h4 otA[4], otB[4];
  #pragma unroll
  for (int nt = 0; nt < 4; ++nt){
    const _Float16* vr = Vt + (nt*16+m)*SVT;
    f4 ca = {0.f,0.f,0.f,0.f};
    f4 cb = {0.f,0.f,0.f,0.f};
    #pragma unroll
    for (int st = 0; st < 6; ++st){
      h4 v = *(const h4*)(vr + ((st*16 + 4*q) ^ swv));
      ca = MFMA4(v, pA[st], ca);
      cb = MFMA4(v, pB[st], cb);
    }
    h4 tA, tB;
    #pragma unroll
    for (int i = 0; i < 4; ++i){ tA[i] = (_Float16)ca[i]; tB[i] = (_Float16)cb[i]; }
    otA[nt] = tA; otB[nt] = tB;
  }
  // O proj (prefetched A-frags) + residual + LN
  f4 vfA[4], vfB[4];
  #pragma unroll
  for (int nt = 0; nt < 4; ++nt){
    f4 ca = {0.f,0.f,0.f,0.f};
    f4 cb = {0.f,0.f,0.f,0.f};
    #pragma unroll
    for (int kt = 0; kt < 4; ++kt){
      ca = MFMA4(wo[nt][kt], otA[kt], ca);
      cb = MFMA4(wo[nt][kt], otB[kt], cb);
    }
    f4 b4 = *(const f4*)(bo + nt*16 + d0);
    #pragma unroll
    for (int i = 0; i < 4; ++i){
      vfA[nt][i] = ca[i] + b4[i] + (float)xA[nt][i];
      vfB[nt][i] = cb[i] + b4[i] + (float)xB[nt][i];
    }
  }
  lnT(vfA, xA, g_, b_, q);
  lnT(vfB, xB, g_, b_, q);
}

// single-tile attention (decoder), Wqt pre-scaled
__device__ __forceinline__ void attnT(h4 xt[4], const _Float16* K, const _Float16* Vt,
        const _Float16* __restrict__ Wqt, const float* __restrict__ bq,
        const _Float16* __restrict__ Wot, const float* __restrict__ bo,
        const float* __restrict__ g_, const float* __restrict__ b_, int q, int m){
  const int d0 = 4*q;
  f4 c[4];
  mm64T(Wqt, 64, xt, c, q, m);
  h4 qt[4];
  #pragma unroll
  for (int nt = 0; nt < 4; ++nt){
    f4 b4 = *(const f4*)(bq + nt*16 + d0);
    h4 o;
    #pragma unroll
    for (int i = 0; i < 4; ++i) o[i] = (_Float16)(c[nt][i] + b4[i]*0.125f);
    qt[nt] = o;
  }
  h4 pt[6];
  scoresT(qt, K, pt, q, m);
  h4 wo[4][4];
  #pragma unroll
  for (int nt = 0; nt < 4; ++nt)
    #pragma unroll
    for (int kt = 0; kt < 4; ++kt)
      wo[nt][kt] = *(const h4*)(Wot + (nt*16+m)*64 + kt*16 + 4*q);
  const int swv = (m & 3) << 3;
  h4 ot[4];
  #pragma unroll
  for (int nt = 0; nt < 4; ++nt){
    const _Float16* vr = Vt + (nt*16+m)*SVT;
    f4 cc = {0.f,0.f,0.f,0.f};
    #pragma unroll
    for (int st = 0; st < 6; ++st){
      h4 v = *(const h4*)(vr + ((st*16 + 4*q) ^ swv));
      cc = MFMA4(v, pt[st], cc);
    }
    h4 t;
    #pragma unroll
    for (int i = 0; i < 4; ++i) t[i] = (_Float16)cc[i];
    ot[nt] = t;
  }
  f4 vf[4];
  #pragma unroll
  for (int nt = 0; nt < 4; ++nt){
    f4 cc = {0.f,0.f,0.f,0.f};
    #pragma unroll
    for (int kt = 0; kt < 4; ++kt)
      cc = MFMA4(wo[nt][kt], ot[kt], cc);
    f4 b4 = *(const f4*)(bo + nt*16 + d0);
    #pragma unroll
    for (int i = 0; i < 4; ++i) vf[nt][i] = cc[i] + b4[i] + (float)xt[nt][i];
  }
  lnT(vf, xt, g_, b_, q);
}

// dual-tile FFN d->d + residual + LN
__device__ __forceinline__ void ffnT2(h4 xA[4], h4 xB[4],
        const _Float16* __restrict__ W1t, const float* __restrict__ b1,
        const _Float16* __restrict__ W2t, const float* __restrict__ b2,
        const float* __restrict__ g_, const float* __restrict__ b_, int q, int m){
  const int d0 = 4*q;
  f4 cA[4], cB[4];
  mm64T2(W1t, 64, xA, xB, cA, cB, q, m);
  h4 hA[4], hB[4];
  #pragma unroll
  for (int nt = 0; nt < 4; ++nt){
    f4 b4 = *(const f4*)(b1 + nt*16 + d0);
    h4 oA, oB;
    #pragma unroll
    for (int i = 0; i < 4; ++i){
      oA[i] = (_Float16)fmaxf(cA[nt][i] + b4[i], 0.f);
      oB[i] = (_Float16)fmaxf(cB[nt][i] + b4[i], 0.f);
    }
    hA[nt] = oA; hB[nt] = oB;
  }
  f4 yA[4], yB[4];
  mm64T2(W2t, 64, hA, hB, yA, yB, q, m);
  f4 vfA[4], vfB[4];
  #pragma unroll
  for (int nt = 0; nt < 4; ++nt){
    f4 b4 = *(const f4*)(b2 + nt*16 + d0);
    #pragma unroll
    for (int i = 0; i < 4; ++i){
      vfA[nt][i] = yA[nt][i] + b4[i] + (float)xA[nt][i];
      vfB[nt][i] = yB[nt][i] + b4[i] + (float)xB[nt][i];
    }
  }
  lnT(vfA, xA, g_, b_, q);
  lnT(vfB, xB, g_, b_, q);
}

// dual-tile K/V build (shared weight loads), XOR-swizzled stores
__device__ __forceinline__ void kvT2(const h4 xA[4], const h4 xB[4], int rA, int rB,
        _Float16* K, _Float16* Vt,
        const _Float16* __restrict__ Wkt, const float* __restrict__ bk,
        const _Float16* __restrict__ Wvt, const float* __restrict__ bv,
        int q, int m){
  const int d0 = 4*q;
  f4 cA[4], cB[4];
  mm64T2(Wkt, 64, xA, xB, cA, cB, q, m);
  const int swk = (m & 7) << 3;        // (r+m)&7 == m&7: rA,rB multiples of 16
  #pragma unroll
  for (int nt = 0; nt < 4; ++nt){
    f4 b4 = *(const f4*)(bk + nt*16 + d0);
    h4 oA, oB;
    #pragma unroll
    for (int i = 0; i < 4; ++i){
      oA[i] = (_Float16)(cA[nt][i] + b4[i]);
      oB[i] = (_Float16)(cB[nt][i] + b4[i]);
    }
    *(h4*)(K + (rA+m)*SXE + ((nt*16 + d0) ^ swk)) = oA;
    *(h4*)(K + (rB+m)*SXE + ((nt*16 + d0) ^ swk)) = oB;
  }
  mm64T2(Wvt, 64, xA, xB, cA, cB, q, m);
  #pragma unroll
  for (int nt = 0; nt < 4; ++nt){
    f4 b4 = *(const f4*)(bv + nt*16 + d0);
    #pragma unroll
    for (int i = 0; i < 4; ++i){
      Vt[(nt*16 + d0 + i)*SVT + ((rA+m) ^ (i<<3))] = (_Float16)(cA[nt][i] + b4[i]);
      Vt[(nt*16 + d0 + i)*SVT + ((rB+m) ^ (i<<3))] = (_Float16)(cB[nt][i] + b4[i]);
    }
  }
}

// T-form conv for one row (lane: row, d = nt*16+4q+i)
__device__ __forceinline__ void convT(h4 xt[4], const float* __restrict__ cw,
                                      float xl, float xc, float xr, float cs_mu, int q){
  const int d0 = 4*q;
  #pragma unroll
  for (int nt = 0; nt < 4; ++nt){
    const float* w = cw + 3*(nt*16 + d0);
    float c0[4], c1[4], c2[4];
    #pragma unroll
    for (int i = 0; i < 4; ++i){ c0[i] = w[3*i]; c1[i] = w[3*i+1]; c2[i] = w[3*i+2]; }
    h4 o;
    #pragma unroll
    for (int i = 0; i < 4; ++i)
      o[i] = (_Float16)(c0[i]*xl + c1[i]*xc + c2[i]*xr - (c0[i]+c1[i]+c2[i])*cs_mu);
    xt[nt] = o;
  }
}

// ---- weight prep: fp32 -> fp16 transposed; Wq pre-scaled by 0.125 (exact) ----
__global__ void prep_weights(Params p, _Float16* ws){
  const float* sq[10] = {p.eWq, p.eWk, p.eWv, p.eWo, p.ec1_w, p.ec2_w,
                         p.dWq, p.dWk, p.dWv, p.dWo};
  for (int idx = blockIdx.x*blockDim.x + threadIdx.x; idx < WS_TOTAL;
       idx += gridDim.x*blockDim.x){
    if (idx < WS_DC1){
      int mi = idx >> 12, r = idx & 4095;
      int nn = r >> 6, k = r & 63;
      float sc = (mi == 0 || mi == 6) ? 0.125f : 1.f;
      ws[idx] = (_Float16)(sq[mi][k*64 + nn] * sc);
    } else if (idx < WS_DC2){
      int r = idx - WS_DC1;
      int nn = r >> 6, k = r & 63;
      ws[idx] = (_Float16)p.dc1_w[k*256 + nn];
    } else {
      int r = idx - WS_DC2;
      int nn = r >> 8, k2 = r & 255;
      ws[idx] = (_Float16)p.dc2_w[k2*64 + nn];
    }
  }
}

// waves_per_eu(3,4): ~128-reg allocator budget (no-spill verified at 84 VGPR).
// Occupancy steps at VGPR 64/128/256 (R3 lesson: VGPR=84 -> 16 waves/CU cap);
// bfrag removal should cut peak VGPR — watch for the 64 step.
__global__ void __launch_bounds__(NTHR)
__attribute__((amdgpu_waves_per_eu(3, 4)))
GraphTransformer_90237262889124_kernel(Params p, const _Float16* __restrict__ ws)
{
  __shared__ __align__(16) _Float16 lds[LDS_HALVES];
  _Float16* K    = lds + K_OFF;
  _Float16* Vt   = lds + VT_OFF;
  float*    serE = (float*)(lds + MISC_OFF);
  float*    serD = serE + 96;
  float*    stat = serD + 144;

  const int tid = threadIdx.x, lane = tid & 63, wave = tid >> 6;
  const int m = lane & 15, q = lane >> 4;
  const int d0 = 4*q;
  const int b = blockIdx.x / NNODE, n = blockIdx.x % NNODE;

  const _Float16* eWq_t = ws + WSQ(0);
  const _Float16* eWk_t = ws + WSQ(1);
  const _Float16* eWv_t = ws + WSQ(2);
  const _Float16* eWo_t = ws + WSQ(3);
  const _Float16* ec1_t = ws + WSQ(4);
  const _Float16* ec2_t = ws + WSQ(5);
  const _Float16* dWq_t = ws + WSQ(6);
  const _Float16* dWk_t = ws + WSQ(7);
  const _Float16* dWv_t = ws + WSQ(8);
  const _Float16* dWo_t = ws + WSQ(9);
  const _Float16* dc1t  = ws + WS_DC1;
  const _Float16* dc2t  = ws + WS_DC2;

  // ---- P0: series loads ----
  if (tid < LE) serE[tid] = p.x_enc[(b*LE + tid)*NNODE + n];
  if (tid >= 48) serD[tid - 48] = p.x_dec[(b*LD + (tid - 48))*NNODE + n];
  __syncthreads();                       // B1
  // ---- P1: means ----
  if (wave == 0){
    float v = serE[lane] + (lane < 32 ? serE[64 + lane] : 0.f);
    float s = wave_sum(v);
    if (lane == 0) stat[0] = s * (1.f/96.f);
  }
  if (wave == 1){
    float v = (lane < OUTL) ? serD[lane] : 0.f;
    float s = wave_sum(v);
    if (lane == 0) stat[1] = s * (1.f/48.f);
  }
  __syncthreads();                       // B2

  const int rA = wave * 16;              // enc tile A rows
  const int rB = (wave + 3) * 16;        // enc tile B rows
  h4 xA[4], xB[4];
  // ---- P2: enc conv (both tiles) + enc K/V ----
  {
    const float mu = stat[0];
    int lA = rA + m;
    int lmA = lA ? lA-1 : LE-1;
    int lpA = (lA == LE-1) ? 0 : lA+1;
    convT(xA, p.enc_conv_w, serE[lmA], serE[lA], serE[lpA], mu, q);
    int lB = rB + m;
    int lmB = lB - 1;                    // rB >= 48, never wraps low
    int lpB = (lB == LE-1) ? 0 : lB+1;
    convT(xB, p.enc_conv_w, serE[lmB], serE[lB], serE[lpB], mu, q);
    kvT2(xA, xB, rA, rB, K, Vt, eWk_t, p.ebk, eWv_t, p.ebv, q, m);
  }
  __syncthreads();                       // B3: enc K/V visible
  // ---- P3: enc attention + FFN (dual-tile) ----
  attnT2(xA, xB, K, Vt, eWq_t, p.ebq, eWo_t, p.ebo, p.en1_g, p.en1_b, q, m);
  ffnT2(xA, xB, ec1_t, p.ec1_b, ec2_t, p.ec2_b, p.en2_g, p.en2_b, q, m);
  __syncthreads();                       // B4: all attn reads done
  // ---- P4: dec cross K/V from enc_out; dec conv hoisted (independent of K/V) ----
  h4 xt[4];
  {
    const float mu = stat[1];
    const int gr = 96 + rA + m;
    float xl = serD[gr-1];
    float xc = serD[gr];
    float xr = (gr == LD-1) ? (serD[0] - mu) : serD[gr+1];
    convT(xt, p.dec_conv_w, xl, xc, xr, 0.f, q);
  }
  kvT2(xA, xB, rA, rB, K, Vt, dWk_t, p.dbk, dWv_t, p.dbv, q, m);
  __syncthreads();                       // B5: dec K/V visible
  // ---- P5: decoder (all 3 waves, one tile each) ----
  {
    attnT(xt, K, Vt, dWq_t, p.dbq, dWo_t, p.dbo, p.dn2_g, p.dn2_b, q, m);
    // FFN d->4d->d, 4 hidden chunks, acc in T-form regs (K=16 path)
    f4 acc[4] = {{0.f,0.f,0.f,0.f},{0.f,0.f,0.f,0.f},{0.f,0.f,0.f,0.f},{0.f,0.f,0.f,0.f}};
    for (int cc = 0; cc < 4; ++cc){
      f4 h[4];
      mm64T(dc1t + cc*4096, 64, xt, h, q, m);
      h4 ht[4];
      #pragma unroll
      for (int nt = 0; nt < 4; ++nt){
        f4 b4 = *(const f4*)(p.dc1_b + cc*64 + nt*16 + d0);
        h4 o;
        #pragma unroll
        for (int i = 0; i < 4; ++i) o[i] = (_Float16)fmaxf(h[nt][i] + b4[i], 0.f);
        ht[nt] = o;
      }
      #pragma unroll
      for (int nt = 0; nt < 4; ++nt){
        const _Float16* ar = dc2t + (nt*16+m)*256 + cc*64 + 4*q;
        #pragma unroll
        for (int kt = 0; kt < 4; ++kt)
          acc[nt] = MFMA4(*(const h4*)(ar + kt*16), ht[kt], acc[nt]);
      }
    }
    // final LN(dn3) + proj + enc-mean
    f4 vf[4];
    #pragma unroll
    for (int nt = 0; nt < 4; ++nt){
      f4 b4 = *(const f4*)(p.dc2_b + nt*16 + d0);
      #pragma unroll
      for (int i = 0; i < 4; ++i) vf[nt][i] = acc[nt][i] + b4[i] + (float)xt[nt][i];
    }
    float s = 0.f;
    #pragma unroll
    for (int nt = 0; nt < 4; ++nt) s += vf[nt][0]+vf[nt][1]+vf[nt][2]+vf[nt][3];
    s = q_sum(s);
    float mu = s * (1.f/64.f);
    float ss = 0.f;
    #pragma unroll
    for (int nt = 0; nt < 4; ++nt)
      #pragma unroll
      for (int i = 0; i < 4; ++i){ float d = vf[nt][i]-mu; ss += d*d; }
    ss = q_sum(ss);
    float rs = rsqrtf(ss * (1.f/64.f) + 1e-5f);
    float pp = 0.f;
    #pragma unroll
    for (int nt = 0; nt < 4; ++nt){
      f4 g4 = *(const f4*)(p.dn3_g + nt*16 + d0);
      f4 b4 = *(const f4*)(p.dn3_b + nt*16 + d0);
      f4 w4 = *(const f4*)(p.proj_w + nt*16 + d0);
      #pragma unroll
      for (int i = 0; i < 4; ++i)
        pp += ((vf[nt][i]-mu)*rs*g4[i] + b4[i]) * w4[i];
    }
    pp = q_sum(pp);
    if (q == 0)
      p.out[(b*OUTL + rA + m)*NNODE + n] = pp + p.proj_b[0] + stat[0];
  }
}

extern "C" void kernel_launch(void* const* d_in, const int* in_sizes, int n_in,
                              void* d_out, int out_size, void* d_ws, size_t ws_size,
                              hipStream_t stream) {
  Params p;
  p.x_enc = (const float*)d_in[0];  p.x_dec = (const float*)d_in[1];
  p.enc_conv_w = (const float*)d_in[4];  p.dec_conv_w = (const float*)d_in[5];
  p.eWq = (const float*)d_in[6];   p.ebq = (const float*)d_in[7];
  p.eWk = (const float*)d_in[8];   p.ebk = (const float*)d_in[9];
  p.eWv = (const float*)d_in[10];  p.ebv = (const float*)d_in[11];
  p.eWo = (const float*)d_in[12];  p.ebo = (const float*)d_in[13];
  p.ec1_w = (const float*)d_in[14]; p.ec1_b = (const float*)d_in[15];
  p.ec2_w = (const float*)d_in[16]; p.ec2_b = (const float*)d_in[17];
  p.en1_g = (const float*)d_in[18]; p.en1_b = (const float*)d_in[19];
  p.en2_g = (const float*)d_in[20]; p.en2_b = (const float*)d_in[21];
  p.dWq = (const float*)d_in[22];  p.dbq = (const float*)d_in[23];
  p.dWk = (const float*)d_in[24];  p.dbk = (const float*)d_in[25];
  p.dWv = (const float*)d_in[26];  p.dbv = (const float*)d_in[27];
  p.dWo = (const float*)d_in[28];  p.dbo = (const float*)d_in[29];
  p.dc1_w = (const float*)d_in[30]; p.dc1_b = (const float*)d_in[31];
  p.dc2_w = (const float*)d_in[32]; p.dc2_b = (const float*)d_in[33];
  p.dn2_g = (const float*)d_in[34]; p.dn2_b = (const float*)d_in[35];
  p.dn3_g = (const float*)d_in[36]; p.dn3_b = (const float*)d_in[37];
  p.proj_w = (const float*)d_in[38]; p.proj_b = (const float*)d_in[39];
  p.out = (float*)d_out;

  _Float16* ws = (_Float16*)d_ws;
  prep_weights<<<144, 512, 0, stream>>>(p, ws);
  GraphTransformer_90237262889124_kernel<<<NSEQ, NTHR, 0, stream>>>(p, ws);
}

// Round 7
// 278.725 us; speedup vs baseline: 2.4713x; 2.4713x over previous
//
#include <hip/hip_runtime.h>

typedef _Float16 h8 __attribute__((ext_vector_type(8)));
typedef _Float16 h4 __attribute__((ext_vector_type(4)));
typedef float    f4 __attribute__((ext_vector_type(4)));

// K=16 MFMA with ALL operands in fragment-major layout: zero cross-lane
// shuffles, zero XOR address math, h8/b128 loads (R4 lesson: event COUNT on
// the serial chain is the bottleneck; R4's h4 loads doubled it).
#define MFMA4(a,b,c) __builtin_amdgcn_mfma_f32_16x16x16f16((a),(b),(c),0,0,0)

#define NSEQ  5200
#define NNODE 325
#define LE    96
#define LD    144
#define OUTL  48
#define NTHR  192   // 3 waves; wave w owns enc tiles w and w+3, dec tile w

// K LDS: frag-major [st][kt2][lane][8]: half-off = st*1024 + kt2*512 + lane*8.
//   Producer lane (m,q) T-form h4 == consumer lane (m,q) A-frag (identity map):
//   write 2x ds_write_b128, read 2x ds_read_b128 per tile, stride-1, conflict-free.
// Vt: [d][kv] row-major, stride 104 halves. kv RANGES 0..95 (6 tiles x 16) --
//   R5 BUG was stride 72 < 96: row aliasing + overflow into serE. 104 = R0's
//   proven stride (odd x8: ~2 lanes/bank for h4 PV reads; 8B-aligned).
#define SVT   104

#define K_OFF    0
#define VT_OFF   6144             // 6 st * 1024 halves
#define MISC_OFF 12800            // + 64*104 = 6656 halves
#define LDS_HALVES 13288          // + 488 halves misc (serE 192 + serD 288 + stat 8) = 26,576 B

// ws layout (halves): frag-major 64x64 blocks of 4096 halves each:
//   off-in-block = nt*1024 + kt2*512 + lane*8 + h,
//   holding W^T[out=nt*16+(lane&15)][k=kt2*32+(h>>2)*16+(lane>>4)*4+(h&3)]
// 10 square mats, then dc1 (4 chunks of 64 out-cols), then dc2 (4 chunks of 64 k).
#define WSQ(i)   ((i)*4096)
#define WS_DC1   40960
#define WS_DC2   57344
#define WS_TOTAL 73728

struct Params {
  const float* x_enc; const float* x_dec;
  const float* enc_conv_w; const float* dec_conv_w;
  const float* eWq; const float* ebq; const float* eWk; const float* ebk;
  const float* eWv; const float* ebv; const float* eWo; const float* ebo;
  const float* ec1_w; const float* ec1_b; const float* ec2_w; const float* ec2_b;
  const float* en1_g; const float* en1_b; const float* en2_g; const float* en2_b;
  const float* dWq; const float* dbq; const float* dWk; const float* dbk;
  const float* dWv; const float* dbv; const float* dWo; const float* dbo;
  const float* dc1_w; const float* dc1_b; const float* dc2_w; const float* dc2_b;
  const float* dn2_g; const float* dn2_b; const float* dn3_g; const float* dn3_b;
  const float* proj_w; const float* proj_b;
  float* out;
};

__device__ __forceinline__ float wave_sum(float v){
  v += __shfl_xor(v, 32, 64); v += __shfl_xor(v, 16, 64);
  v += __shfl_xor(v,  8, 64); v += __shfl_xor(v,  4, 64);
  v += __shfl_xor(v,  2, 64); v += __shfl_xor(v,  1, 64);
  return v;
}
__device__ __forceinline__ float q_sum(float v){
  v += __shfl_xor(v, 16, 64); v += __shfl_xor(v, 32, 64); return v;
}

__device__ __forceinline__ h4 lo4(h8 v){ return __builtin_shufflevector(v, v, 0,1,2,3); }
__device__ __forceinline__ h4 hi4(h8 v){ return __builtin_shufflevector(v, v, 4,5,6,7); }
__device__ __forceinline__ h8 cat8(h4 a, h4 b){ return __builtin_shufflevector(a, b, 0,1,2,3,4,5,6,7); }

// dual-tile Y^T = A @ t, frag-major A (global), shared A loads (8x h8 = R0 count)
__device__ __forceinline__ void mm64T2(const _Float16* __restrict__ A,
                                       const h4 ta[4], const h4 tb[4],
                                       f4 oa[4], f4 ob[4], int lane){
  #pragma unroll
  for (int nt = 0; nt < 4; ++nt){
    const _Float16* ar = A + (nt*128 + lane)*8;
    h8 w0 = *(const h8*)(ar);
    h8 w1 = *(const h8*)(ar + 512);
    f4 ca = {0.f,0.f,0.f,0.f}, cb = {0.f,0.f,0.f,0.f};
    ca = MFMA4(lo4(w0), ta[0], ca);  cb = MFMA4(lo4(w0), tb[0], cb);
    ca = MFMA4(hi4(w0), ta[1], ca);  cb = MFMA4(hi4(w0), tb[1], cb);
    ca = MFMA4(lo4(w1), ta[2], ca);  cb = MFMA4(lo4(w1), tb[2], cb);
    ca = MFMA4(hi4(w1), ta[3], ca);  cb = MFMA4(hi4(w1), tb[3], cb);
    oa[nt] = ca; ob[nt] = cb;
  }
}
// single-tile variant (decoder)
__device__ __forceinline__ void mm64T(const _Float16* __restrict__ A,
                                      const h4 t[4], f4 out[4], int lane){
  #pragma unroll
  for (int nt = 0; nt < 4; ++nt){
    const _Float16* ar = A + (nt*128 + lane)*8;
    h8 w0 = *(const h8*)(ar);
    h8 w1 = *(const h8*)(ar + 512);
    f4 c = {0.f,0.f,0.f,0.f};
    c = MFMA4(lo4(w0), t[0], c);
    c = MFMA4(hi4(w0), t[1], c);
    c = MFMA4(lo4(w1), t[2], c);
    c = MFMA4(hi4(w1), t[3], c);
    out[nt] = c;
  }
}

// LN over d (lane-local 16 + cross-q) -> updates xt
__device__ __forceinline__ void lnT(const f4 vf[4], h4 xt[4],
        const float* __restrict__ g_, const float* __restrict__ b_, int q){
  const int d0 = 4*q;
  float s = 0.f;
  #pragma unroll
  for (int nt = 0; nt < 4; ++nt) s += vf[nt][0]+vf[nt][1]+vf[nt][2]+vf[nt][3];
  s = q_sum(s);
  float mu = s * (1.f/64.f);
  float ss = 0.f;
  #pragma unroll
  for (int nt = 0; nt < 4; ++nt)
    #pragma unroll
    for (int i = 0; i < 4; ++i){ float d = vf[nt][i]-mu; ss += d*d; }
  ss = q_sum(ss);
  float rs = rsqrtf(ss * (1.f/64.f) + 1e-5f);
  #pragma unroll
  for (int nt = 0; nt < 4; ++nt){
    f4 g4 = *(const f4*)(g_ + nt*16 + d0);
    f4 b4 = *(const f4*)(b_ + nt*16 + d0);
    h4 o;
    #pragma unroll
    for (int i = 0; i < 4; ++i) o[i] = (_Float16)((vf[nt][i]-mu)*rs*g4[i] + b4[i]);
    xt[nt] = o;
  }
}

// scores from frag-major K (2x ds_read_b128 per tile, conflict-free) +
// max-free softmax (Wq pre-scaled by 0.125; magnitudes O(0.3), exp safe).
__device__ __forceinline__ void scoresT(const h4 qt[4], const _Float16* Kf,
                                        h4 pt[6], int lane){
  f4 s[6];
  #pragma unroll
  for (int st = 0; st < 6; ++st){
    const _Float16* kr = Kf + st*1024 + lane*8;
    h8 w0 = *(const h8*)(kr);
    h8 w1 = *(const h8*)(kr + 512);
    f4 cc = {0.f,0.f,0.f,0.f};
    cc = MFMA4(lo4(w0), qt[0], cc);
    cc = MFMA4(hi4(w0), qt[1], cc);
    cc = MFMA4(lo4(w1), qt[2], cc);
    cc = MFMA4(hi4(w1), qt[3], cc);
    s[st] = cc;
  }
  float sm = 0.f;
  #pragma unroll
  for (int st = 0; st < 6; ++st)
    #pragma unroll
    for (int i = 0; i < 4; ++i){ float e = __expf(s[st][i]); s[st][i] = e; sm += e; }
  sm = q_sum(sm);
  float r = 1.f/sm;
  #pragma unroll
  for (int st = 0; st < 6; ++st){
    h4 o;
    #pragma unroll
    for (int i = 0; i < 4; ++i) o[i] = (_Float16)(s[st][i]*r);
    pt[st] = o;
  }
}

// dual-tile attention + residual + LN. pt[st] is directly the PV B-frag.
__device__ __forceinline__ void attnT2(h4 xA[4], h4 xB[4],
        const _Float16* Kf, const _Float16* Vt,
        const _Float16* __restrict__ Wqt, const float* __restrict__ bq,
        const _Float16* __restrict__ Wot, const float* __restrict__ bo,
        const float* __restrict__ g_, const float* __restrict__ b_,
        int lane, int m, int q){
  const int d0 = 4*q;
  f4 cA[4], cB[4];
  mm64T2(Wqt, xA, xB, cA, cB, lane);
  h4 qA[4], qB[4];
  #pragma unroll
  for (int nt = 0; nt < 4; ++nt){
    f4 b4 = *(const f4*)(bq + nt*16 + d0);
    h4 oA, oB;
    #pragma unroll
    for (int i = 0; i < 4; ++i){
      oA[i] = (_Float16)(cA[nt][i] + b4[i]*0.125f);
      oB[i] = (_Float16)(cB[nt][i] + b4[i]*0.125f);
    }
    qA[nt] = oA; qB[nt] = oB;
  }
  h4 pA[6], pB[6];
  scoresT(qA, Kf, pA, lane);
  scoresT(qB, Kf, pB, lane);
  // Prefetch Wo A-frags (global latency hides under PV)
  h8 wo0[4], wo1[4];
  #pragma unroll
  for (int nt = 0; nt < 4; ++nt){
    const _Float16* ar = Wot + (nt*128 + lane)*8;
    wo0[nt] = *(const h8*)(ar);
    wo1[nt] = *(const h8*)(ar + 512);
  }
  // O^T = V^T @ P^T, shared V loads, dep chains split 3+3
  h4 otA[4], otB[4];
  #pragma unroll
  for (int nt = 0; nt < 4; ++nt){
    const _Float16* vr = Vt + (nt*16+m)*SVT + 4*q;
    f4 ca0 = {0.f,0.f,0.f,0.f}, cb0 = {0.f,0.f,0.f,0.f};
    f4 ca1 = {0.f,0.f,0.f,0.f}, cb1 = {0.f,0.f,0.f,0.f};
    #pragma unroll
    for (int st = 0; st < 3; ++st){
      h4 v = *(const h4*)(vr + st*16);
      ca0 = MFMA4(v, pA[st], ca0);
      cb0 = MFMA4(v, pB[st], cb0);
    }
    #pragma unroll
    for (int st = 3; st < 6; ++st){
      h4 v = *(const h4*)(vr + st*16);
      ca1 = MFMA4(v, pA[st], ca1);
      cb1 = MFMA4(v, pB[st], cb1);
    }
    f4 ca = ca0 + ca1, cb = cb0 + cb1;
    h4 tA, tB;
    #pragma unroll
    for (int i = 0; i < 4; ++i){ tA[i] = (_Float16)ca[i]; tB[i] = (_Float16)cb[i]; }
    otA[nt] = tA; otB[nt] = tB;
  }
  // O proj (prefetched frags) + residual + LN
  f4 vfA[4], vfB[4];
  #pragma unroll
  for (int nt = 0; nt < 4; ++nt){
    f4 ca = {0.f,0.f,0.f,0.f}, cb = {0.f,0.f,0.f,0.f};
    ca = MFMA4(lo4(wo0[nt]), otA[0], ca);  cb = MFMA4(lo4(wo0[nt]), otB[0], cb);
    ca = MFMA4(hi4(wo0[nt]), otA[1], ca);  cb = MFMA4(hi4(wo0[nt]), otB[1], cb);
    ca = MFMA4(lo4(wo1[nt]), otA[2], ca);  cb = MFMA4(lo4(wo1[nt]), otB[2], cb);
    ca = MFMA4(hi4(wo1[nt]), otA[3], ca);  cb = MFMA4(hi4(wo1[nt]), otB[3], cb);
    f4 b4 = *(const f4*)(bo + nt*16 + d0);
    #pragma unroll
    for (int i = 0; i < 4; ++i){
      vfA[nt][i] = ca[i] + b4[i] + (float)xA[nt][i];
      vfB[nt][i] = cb[i] + b4[i] + (float)xB[nt][i];
    }
  }
  lnT(vfA, xA, g_, b_, q);
  lnT(vfB, xB, g_, b_, q);
}

// single-tile attention (decoder)
__device__ __forceinline__ void attnT(h4 xt[4], const _Float16* Kf, const _Float16* Vt,
        const _Float16* __restrict__ Wqt, const float* __restrict__ bq,
        const _Float16* __restrict__ Wot, const float* __restrict__ bo,
        const float* __restrict__ g_, const float* __restrict__ b_,
        int lane, int m, int q){
  const int d0 = 4*q;
  f4 c[4];
  mm64T(Wqt, xt, c, lane);
  h4 qt[4];
  #pragma unroll
  for (int nt = 0; nt < 4; ++nt){
    f4 b4 = *(const f4*)(bq + nt*16 + d0);
    h4 o;
    #pragma unroll
    for (int i = 0; i < 4; ++i) o[i] = (_Float16)(c[nt][i] + b4[i]*0.125f);
    qt[nt] = o;
  }
  h4 pt[6];
  scoresT(qt, Kf, pt, lane);
  h8 wo0[4], wo1[4];
  #pragma unroll
  for (int nt = 0; nt < 4; ++nt){
    const _Float16* ar = Wot + (nt*128 + lane)*8;
    wo0[nt] = *(const h8*)(ar);
    wo1[nt] = *(const h8*)(ar + 512);
  }
  h4 ot[4];
  #pragma unroll
  for (int nt = 0; nt < 4; ++nt){
    const _Float16* vr = Vt + (nt*16+m)*SVT + 4*q;
    f4 c0 = {0.f,0.f,0.f,0.f}, c1 = {0.f,0.f,0.f,0.f};
    #pragma unroll
    for (int st = 0; st < 3; ++st)
      c0 = MFMA4(*(const h4*)(vr + st*16), pt[st], c0);
    #pragma unroll
    for (int st = 3; st < 6; ++st)
      c1 = MFMA4(*(const h4*)(vr + st*16), pt[st], c1);
    f4 cc = c0 + c1;
    h4 t;
    #pragma unroll
    for (int i = 0; i < 4; ++i) t[i] = (_Float16)cc[i];
    ot[nt] = t;
  }
  f4 vf[4];
  #pragma unroll
  for (int nt = 0; nt < 4; ++nt){
    f4 cc = {0.f,0.f,0.f,0.f};
    cc = MFMA4(lo4(wo0[nt]), ot[0], cc);
    cc = MFMA4(hi4(wo0[nt]), ot[1], cc);
    cc = MFMA4(lo4(wo1[nt]), ot[2], cc);
    cc = MFMA4(hi4(wo1[nt]), ot[3], cc);
    f4 b4 = *(const f4*)(bo + nt*16 + d0);
    #pragma unroll
    for (int i = 0; i < 4; ++i) vf[nt][i] = cc[i] + b4[i] + (float)xt[nt][i];
  }
  lnT(vf, xt, g_, b_, q);
}

// dual-tile FFN d->d + residual + LN
__device__ __forceinline__ void ffnT2(h4 xA[4], h4 xB[4],
        const _Float16* __restrict__ W1t, const float* __restrict__ b1,
        const _Float16* __restrict__ W2t, const float* __restrict__ b2,
        const float* __restrict__ g_, const float* __restrict__ b_,
        int lane, int q){
  const int d0 = 4*q;
  f4 cA[4], cB[4];
  mm64T2(W1t, xA, xB, cA, cB, lane);
  h4 hA[4], hB[4];
  #pragma unroll
  for (int nt = 0; nt < 4; ++nt){
    f4 b4 = *(const f4*)(b1 + nt*16 + d0);
    h4 oA, oB;
    #pragma unroll
    for (int i = 0; i < 4; ++i){
      oA[i] = (_Float16)fmaxf(cA[nt][i] + b4[i], 0.f);
      oB[i] = (_Float16)fmaxf(cB[nt][i] + b4[i], 0.f);
    }
    hA[nt] = oA; hB[nt] = oB;
  }
  f4 yA[4], yB[4];
  mm64T2(W2t, hA, hB, yA, yB, lane);
  f4 vfA[4], vfB[4];
  #pragma unroll
  for (int nt = 0; nt < 4; ++nt){
    f4 b4 = *(const f4*)(b2 + nt*16 + d0);
    #pragma unroll
    for (int i = 0; i < 4; ++i){
      vfA[nt][i] = yA[nt][i] + b4[i] + (float)xA[nt][i];
      vfB[nt][i] = yB[nt][i] + b4[i] + (float)xB[nt][i];
    }
  }
  lnT(vfA, xA, g_, b_, q);
  lnT(vfB, xB, g_, b_, q);
}

// dual-tile K/V build: K written frag-major (2x b128/tile, conflict-free);
// Vt scatter [d][kv] stride 104.
__device__ __forceinline__ void kvT2(const h4 xA[4], const h4 xB[4], int rA, int rB,
        _Float16* Kf, _Float16* Vt,
        const _Float16* __restrict__ Wkt, const float* __restrict__ bk,
        const _Float16* __restrict__ Wvt, const float* __restrict__ bv,
        int lane, int m, int q){
  const int d0 = 4*q;
  f4 cA[4], cB[4];
  mm64T2(Wkt, xA, xB, cA, cB, lane);
  {
    h4 oA[4], oB[4];
    #pragma unroll
    for (int nt = 0; nt < 4; ++nt){
      f4 b4 = *(const f4*)(bk + nt*16 + d0);
      #pragma unroll
      for (int i = 0; i < 4; ++i){
        oA[nt][i] = (_Float16)(cA[nt][i] + b4[i]);
        oB[nt][i] = (_Float16)(cB[nt][i] + b4[i]);
      }
    }
    const int stA = rA >> 4, stB = rB >> 4;
    *(h8*)(Kf + stA*1024       + lane*8) = cat8(oA[0], oA[1]);
    *(h8*)(Kf + stA*1024 + 512 + lane*8) = cat8(oA[2], oA[3]);
    *(h8*)(Kf + stB*1024       + lane*8) = cat8(oB[0], oB[1]);
    *(h8*)(Kf + stB*1024 + 512 + lane*8) = cat8(oB[2], oB[3]);
  }
  mm64T2(Wvt, xA, xB, cA, cB, lane);
  #pragma unroll
  for (int nt = 0; nt < 4; ++nt){
    f4 b4 = *(const f4*)(bv + nt*16 + d0);
    #pragma unroll
    for (int i = 0; i < 4; ++i){
      Vt[(nt*16 + d0 + i)*SVT + rA + m] = (_Float16)(cA[nt][i] + b4[i]);
      Vt[(nt*16 + d0 + i)*SVT + rB + m] = (_Float16)(cB[nt][i] + b4[i]);
    }
  }
}

// T-form conv for one row (lane: row, d = nt*16+4q+i)
__device__ __forceinline__ void convT(h4 xt[4], const float* __restrict__ cw,
                                      float xl, float xc, float xr, float cs_mu, int q){
  const int d0 = 4*q;
  #pragma unroll
  for (int nt = 0; nt < 4; ++nt){
    const float* w = cw + 3*(nt*16 + d0);
    float c0[4], c1[4], c2[4];
    #pragma unroll
    for (int i = 0; i < 4; ++i){ c0[i] = w[3*i]; c1[i] = w[3*i+1]; c2[i] = w[3*i+2]; }
    h4 o;
    #pragma unroll
    for (int i = 0; i < 4; ++i)
      o[i] = (_Float16)(c0[i]*xl + c1[i]*xc + c2[i]*xr - (c0[i]+c1[i]+c2[i])*cs_mu);
    xt[nt] = o;
  }
}

// ---- weight prep: fp32 -> fp16, FRAG-MAJOR; Wq pre-scaled by 0.125 (exact) ----
// In-block decode: h=idx&7, l=(idx>>3)&63, kt2=(idx>>9)&1, nt=(idx>>10)&3;
// out-row = nt*16+(l&15); k = kt2*32+(h>>2)*16+(l>>4)*4+(h&3).
__global__ void prep_weights(Params p, _Float16* ws){
  const float* sq[10] = {p.eWq, p.eWk, p.eWv, p.eWo, p.ec1_w, p.ec2_w,
                         p.dWq, p.dWk, p.dWv, p.dWo};
  for (int idx = blockIdx.x*blockDim.x + threadIdx.x; idx < WS_TOTAL;
       idx += gridDim.x*blockDim.x){
    int r  = idx & 4095;
    int h  = r & 7, l = (r>>3) & 63, kt2 = (r>>9) & 1, nt = r>>10;
    int m  = l & 15, q = l >> 4;
    int orow = nt*16 + m;
    int kk   = kt2*32 + (h>>2)*16 + q*4 + (h&3);
    float v;
    if (idx < WS_DC1){
      int mi = idx >> 12;
      float sc = (mi == 0 || mi == 6) ? 0.125f : 1.f;
      v = sq[mi][kk*64 + orow] * sc;
    } else if (idx < WS_DC2){
      int cc = (idx - WS_DC1) >> 12;
      v = p.dc1_w[kk*256 + cc*64 + orow];
    } else {
      int cc = (idx - WS_DC2) >> 12;
      v = p.dc2_w[(cc*64 + kk)*64 + orow];
    }
    ws[idx] = (_Float16)v;
  }
}

// waves_per_eu(3,4): ~128-reg allocator budget (no-spill verified at 84 VGPR).
__global__ void __launch_bounds__(NTHR)
__attribute__((amdgpu_waves_per_eu(3, 4)))
GraphTransformer_90237262889124_kernel(Params p, const _Float16* __restrict__ ws)
{
  __shared__ __align__(16) _Float16 lds[LDS_HALVES];
  _Float16* Kf   = lds + K_OFF;
  _Float16* Vt   = lds + VT_OFF;
  float*    serE = (float*)(lds + MISC_OFF);
  float*    serD = serE + 96;
  float*    stat = serD + 144;

  const int tid = threadIdx.x, lane = tid & 63, wave = tid >> 6;
  const int m = lane & 15, q = lane >> 4;
  const int d0 = 4*q;
  const int b = blockIdx.x / NNODE, n = blockIdx.x % NNODE;

  const _Float16* eWq_t = ws + WSQ(0);
  const _Float16* eWk_t = ws + WSQ(1);
  const _Float16* eWv_t = ws + WSQ(2);
  const _Float16* eWo_t = ws + WSQ(3);
  const _Float16* ec1_t = ws + WSQ(4);
  const _Float16* ec2_t = ws + WSQ(5);
  const _Float16* dWq_t = ws + WSQ(6);
  const _Float16* dWk_t = ws + WSQ(7);
  const _Float16* dWv_t = ws + WSQ(8);
  const _Float16* dWo_t = ws + WSQ(9);
  const _Float16* dc1f  = ws + WS_DC1;
  const _Float16* dc2f  = ws + WS_DC2;

  // ---- P0: series loads ----
  if (tid < LE) serE[tid] = p.x_enc[(b*LE + tid)*NNODE + n];
  if (tid >= 48) serD[tid - 48] = p.x_dec[(b*LD + (tid - 48))*NNODE + n];
  __syncthreads();                       // B1
  // ---- P1: means ----
  if (wave == 0){
    float v = serE[lane] + (lane < 32 ? serE[64 + lane] : 0.f);
    float s = wave_sum(v);
    if (lane == 0) stat[0] = s * (1.f/96.f);
  }
  if (wave == 1){
    float v = (lane < OUTL) ? serD[lane] : 0.f;
    float s = wave_sum(v);
    if (lane == 0) stat[1] = s * (1.f/48.f);
  }
  __syncthreads();                       // B2

  const int rA = wave * 16;              // enc tile A rows
  const int rB = (wave + 3) * 16;        // enc tile B rows
  h4 xA[4], xB[4];
  // ---- P2: enc conv (both tiles) + enc K/V ----
  {
    const float mu = stat[0];
    int lA = rA + m;
    int lmA = lA ? lA-1 : LE-1;
    int lpA = (lA == LE-1) ? 0 : lA+1;
    convT(xA, p.enc_conv_w, serE[lmA], serE[lA], serE[lpA], mu, q);
    int lB = rB + m;
    int lmB = lB - 1;                    // rB >= 48, never wraps low
    int lpB = (lB == LE-1) ? 0 : lB+1;
    convT(xB, p.enc_conv_w, serE[lmB], serE[lB], serE[lpB], mu, q);
    kvT2(xA, xB, rA, rB, Kf, Vt, eWk_t, p.ebk, eWv_t, p.ebv, lane, m, q);
  }
  __syncthreads();                       // B3: enc K/V visible
  // ---- P3: enc attention + FFN (dual-tile) ----
  attnT2(xA, xB, Kf, Vt, eWq_t, p.ebq, eWo_t, p.ebo, p.en1_g, p.en1_b, lane, m, q);
  ffnT2(xA, xB, ec1_t, p.ec1_b, ec2_t, p.ec2_b, p.en2_g, p.en2_b, lane, q);
  __syncthreads();                       // B4: all attn reads done
  // ---- P4: dec cross K/V from enc_out; dec conv hoisted ----
  h4 xt[4];
  {
    const float mu = stat[1];
    const int gr = 96 + rA + m;
    float xl = serD[gr-1];
    float xc = serD[gr];
    float xr = (gr == LD-1) ? (serD[0] - mu) : serD[gr+1];
    convT(xt, p.dec_conv_w, xl, xc, xr, 0.f, q);
  }
  kvT2(xA, xB, rA, rB, Kf, Vt, dWk_t, p.dbk, dWv_t, p.dbv, lane, m, q);
  __syncthreads();                       // B5: dec K/V visible
  // ---- P5: decoder (all 3 waves, one tile each) ----
  {
    attnT(xt, Kf, Vt, dWq_t, p.dbq, dWo_t, p.dbo, p.dn2_g, p.dn2_b, lane, m, q);
    // FFN d->4d->d, 4 hidden chunks, frag-major dc1/dc2
    f4 acc[4] = {{0.f,0.f,0.f,0.f},{0.f,0.f,0.f,0.f},{0.f,0.f,0.f,0.f},{0.f,0.f,0.f,0.f}};
    for (int cc2 = 0; cc2 < 4; ++cc2){
      f4 hh[4];
      mm64T(dc1f + cc2*4096, xt, hh, lane);
      h4 ht[4];
      #pragma unroll
      for (int nt = 0; nt < 4; ++nt){
        f4 b4 = *(const f4*)(p.dc1_b + cc2*64 + nt*16 + d0);
        h4 o;
        #pragma unroll
        for (int i = 0; i < 4; ++i) o[i] = (_Float16)fmaxf(hh[nt][i] + b4[i], 0.f);
        ht[nt] = o;
      }
      #pragma unroll
      for (int nt = 0; nt < 4; ++nt){
        const _Float16* ar = dc2f + cc2*4096 + (nt*128 + lane)*8;
        h8 w0 = *(const h8*)(ar);
        h8 w1 = *(const h8*)(ar + 512);
        acc[nt] = MFMA4(lo4(w0), ht[0], acc[nt]);
        acc[nt] = MFMA4(hi4(w0), ht[1], acc[nt]);
        acc[nt] = MFMA4(lo4(w1), ht[2], acc[nt]);
        acc[nt] = MFMA4(hi4(w1), ht[3], acc[nt]);
      }
    }
    // final LN(dn3) + proj + enc-mean
    f4 vf[4];
    #pragma unroll
    for (int nt = 0; nt < 4; ++nt){
      f4 b4 = *(const f4*)(p.dc2_b + nt*16 + d0);
      #pragma unroll
      for (int i = 0; i < 4; ++i) vf[nt][i] = acc[nt][i] + b4[i] + (float)xt[nt][i];
    }
    float s = 0.f;
    #pragma unroll
    for (int nt = 0; nt < 4; ++nt) s += vf[nt][0]+vf[nt][1]+vf[nt][2]+vf[nt][3];
    s = q_sum(s);
    float mu = s * (1.f/64.f);
    float ss = 0.f;
    #pragma unroll
    for (int nt = 0; nt < 4; ++nt)
      #pragma unroll
      for (int i = 0; i < 4; ++i){ float d = vf[nt][i]-mu; ss += d*d; }
    ss = q_sum(ss);
    float rs = rsqrtf(ss * (1.f/64.f) + 1e-5f);
    float pp = 0.f;
    #pragma unroll
    for (int nt = 0; nt < 4; ++nt){
      f4 g4 = *(const f4*)(p.dn3_g + nt*16 + d0);
      f4 b4 = *(const f4*)(p.dn3_b + nt*16 + d0);
      f4 w4 = *(const f4*)(p.proj_w + nt*16 + d0);
      #pragma unroll
      for (int i = 0; i < 4; ++i)
        pp += ((vf[nt][i]-mu)*rs*g4[i] + b4[i]) * w4[i];
    }
    pp = q_sum(pp);
    if (q == 0)
      p.out[(b*OUTL + rA + m)*NNODE + n] = pp + p.proj_b[0] + stat[0];
  }
}

extern "C" void kernel_launch(void* const* d_in, const int* in_sizes, int n_in,
                              void* d_out, int out_size, void* d_ws, size_t ws_size,
                              hipStream_t stream) {
  Params p;
  p.x_enc = (const float*)d_in[0];  p.x_dec = (const float*)d_in[1];
  p.enc_conv_w = (const float*)d_in[4];  p.dec_conv_w = (const float*)d_in[5];
  p.eWq = (const float*)d_in[6];   p.ebq = (const float*)d_in[7];
  p.eWk = (const float*)d_in[8];   p.ebk = (const float*)d_in[9];
  p.eWv = (const float*)d_in[10];  p.ebv = (const float*)d_in[11];
  p.eWo = (const float*)d_in[12];  p.ebo = (const float*)d_in[13];
  p.ec1_w = (const float*)d_in[14]; p.ec1_b = (const float*)d_in[15];
  p.ec2_w = (const float*)d_in[16]; p.ec2_b = (const float*)d_in[17];
  p.en1_g = (const float*)d_in[18]; p.en1_b = (const float*)d_in[19];
  p.en2_g = (const float*)d_in[20]; p.en2_b = (const float*)d_in[21];
  p.dWq = (const float*)d_in[22];  p.dbq = (const float*)d_in[23];
  p.dWk = (const float*)d_in[24];  p.dbk = (const float*)d_in[25];
  p.dWv = (const float*)d_in[26];  p.dbv = (const float*)d_in[27];
  p.dWo = (const float*)d_in[28];  p.dbo = (const float*)d_in[29];
  p.dc1_w = (const float*)d_in[30]; p.dc1_b = (const float*)d_in[31];
  p.dc2_w = (const float*)d_in[32]; p.dc2_b = (const float*)d_in[33];
  p.dn2_g = (const float*)d_in[34]; p.dn2_b = (const float*)d_in[35];
  p.dn3_g = (const float*)d_in[36]; p.dn3_b = (const float*)d_in[37];
  p.proj_w = (const float*)d_in[38]; p.proj_b = (const float*)d_in[39];
  p.out = (float*)d_out;

  _Float16* ws = (_Float16*)d_ws;
  prep_weights<<<144, 512, 0, stream>>>(p, ws);
  GraphTransformer_90237262889124_kernel<<<NSEQ, NTHR, 0, stream>>>(p, ws);
}

// Round 9
// 276.334 us; speedup vs baseline: 2.4927x; 1.0087x over previous
//
#include <hip/hip_runtime.h>

typedef _Float16 h8 __attribute__((ext_vector_type(8)));
typedef _Float16 h4 __attribute__((ext_vector_type(4)));
typedef _Float16 h2 __attribute__((ext_vector_type(2)));
typedef float    f4 __attribute__((ext_vector_type(4)));

// K=16 MFMA, all operands fragment-major (R7-verified: 337->190us).
// R8: VALU trim -- bias via MFMA C-init, deferred softmax norm, packed cvt.
#define MFMA4(a,b,c) __builtin_amdgcn_mfma_f32_16x16x16f16((a),(b),(c),0,0,0)

#define NSEQ  5200
#define NNODE 325
#define LE    96
#define LD    144
#define OUTL  48
#define NTHR  192   // 3 waves; wave w owns enc tiles w and w+3, dec tile w

// K LDS: frag-major [st][kt2][lane][8] (identity producer->consumer lane map).
// Vt: [d][kv] stride 104 (kv 0..95; R5 lesson: stride must cover 96).
#define SVT   104

#define K_OFF    0
#define VT_OFF   6144             // 6 st * 1024 halves
#define MISC_OFF 12800            // + 64*104 = 6656 halves
#define LDS_HALVES 13288          // 26,576 B -> 6 blocks/CU (LDS floor: K+Vt data)

// ws: 10 frag-major 64x64 mats + dc1 + dc2, then 128 fp32 pre-scaled q-biases
#define WSQ(i)   ((i)*4096)
#define WS_DC1   40960
#define WS_DC2   57344
#define WS_BQ    73728            // fp32: ebq*0.125 [64], dbq*0.125 [64]
#define WS_TOTAL 73728

struct Params {
  const float* x_enc; const float* x_dec;
  const float* enc_conv_w; const float* dec_conv_w;
  const float* eWq; const float* ebq; const float* eWk; const float* ebk;
  const float* eWv; const float* ebv; const float* eWo; const float* ebo;
  const float* ec1_w; const float* ec1_b; const float* ec2_w; const float* ec2_b;
  const float* en1_g; const float* en1_b; const float* en2_g; const float* en2_b;
  const float* dWq; const float* dbq; const float* dWk; const float* dbk;
  const float* dWv; const float* dbv; const float* dWo; const float* dbo;
  const float* dc1_w; const float* dc1_b; const float* dc2_w; const float* dc2_b;
  const float* dn2_g; const float* dn2_b; const float* dn3_g; const float* dn3_b;
  const float* proj_w; const float* proj_b;
  float* out;
};

__device__ __forceinline__ float wave_sum(float v){
  v += __shfl_xor(v, 32, 64); v += __shfl_xor(v, 16, 64);
  v += __shfl_xor(v,  8, 64); v += __shfl_xor(v,  4, 64);
  v += __shfl_xor(v,  2, 64); v += __shfl_xor(v,  1, 64);
  return v;
}
__device__ __forceinline__ float q_sum(float v){
  v += __shfl_xor(v, 16, 64); v += __shfl_xor(v, 32, 64); return v;
}

__device__ __forceinline__ h4 lo4(h8 v){ return __builtin_shufflevector(v, v, 0,1,2,3); }
__device__ __forceinline__ h4 hi4(h8 v){ return __builtin_shufflevector(v, v, 4,5,6,7); }
__device__ __forceinline__ h8 cat8(h4 a, h4 b){ return __builtin_shufflevector(a, b, 0,1,2,3,4,5,6,7); }

// packed f32x4 -> f16x4 (2x v_cvt_pkrtz instead of 4x v_cvt_f16_f32).
// R8 compile fix: builtin returns __fp16x2 -> bit_cast to h2.
__device__ __forceinline__ h4 pk4(f4 v){
  h2 a = __builtin_bit_cast(h2, __builtin_amdgcn_cvt_pkrtz(v[0], v[1]));
  h2 b = __builtin_bit_cast(h2, __builtin_amdgcn_cvt_pkrtz(v[2], v[3]));
  return __builtin_shufflevector(a, b, 0,1,2,3);
}
__device__ __forceinline__ h4 relu_pk(f4 v){
  f4 r;
  #pragma unroll
  for (int i = 0; i < 4; ++i) r[i] = fmaxf(v[i], 0.f);
  return pk4(r);
}

// dual-tile Y^T = A @ t + bias (bias -> MFMA C-init; saves post-adds)
__device__ __forceinline__ void mm64T2(const _Float16* __restrict__ A,
                                       const h4 ta[4], const h4 tb[4],
                                       f4 oa[4], f4 ob[4], int lane,
                                       const float* __restrict__ bias, int d0){
  #pragma unroll
  for (int nt = 0; nt < 4; ++nt){
    const _Float16* ar = A + (nt*128 + lane)*8;
    h8 w0 = *(const h8*)(ar);
    h8 w1 = *(const h8*)(ar + 512);
    f4 b4 = *(const f4*)(bias + nt*16 + d0);
    f4 ca = b4, cb = b4;
    ca = MFMA4(lo4(w0), ta[0], ca);  cb = MFMA4(lo4(w0), tb[0], cb);
    ca = MFMA4(hi4(w0), ta[1], ca);  cb = MFMA4(hi4(w0), tb[1], cb);
    ca = MFMA4(lo4(w1), ta[2], ca);  cb = MFMA4(lo4(w1), tb[2], cb);
    ca = MFMA4(hi4(w1), ta[3], ca);  cb = MFMA4(hi4(w1), tb[3], cb);
    oa[nt] = ca; ob[nt] = cb;
  }
}
// single-tile variant (decoder)
__device__ __forceinline__ void mm64T(const _Float16* __restrict__ A,
                                      const h4 t[4], f4 out[4], int lane,
                                      const float* __restrict__ bias, int d0){
  #pragma unroll
  for (int nt = 0; nt < 4; ++nt){
    const _Float16* ar = A + (nt*128 + lane)*8;
    h8 w0 = *(const h8*)(ar);
    h8 w1 = *(const h8*)(ar + 512);
    f4 c = *(const f4*)(bias + nt*16 + d0);
    c = MFMA4(lo4(w0), t[0], c);
    c = MFMA4(hi4(w0), t[1], c);
    c = MFMA4(lo4(w1), t[2], c);
    c = MFMA4(hi4(w1), t[3], c);
    out[nt] = c;
  }
}

// LN: single-pass sum/sumsq + fused fma normalize + packed cvt
__device__ __forceinline__ void lnT(const f4 vf[4], h4 xt[4],
        const float* __restrict__ g_, const float* __restrict__ b_, int q){
  const int d0 = 4*q;
  float s = 0.f, s2 = 0.f;
  #pragma unroll
  for (int nt = 0; nt < 4; ++nt)
    #pragma unroll
    for (int i = 0; i < 4; ++i){ float v = vf[nt][i]; s += v; s2 = fmaf(v, v, s2); }
  s = q_sum(s); s2 = q_sum(s2);
  float mu = s * (1.f/64.f);
  float rs = rsqrtf(fmaxf(s2 * (1.f/64.f) - mu*mu, 0.f) + 1e-5f);
  #pragma unroll
  for (int nt = 0; nt < 4; ++nt){
    f4 g4 = *(const f4*)(g_ + nt*16 + d0);
    f4 b4 = *(const f4*)(b_ + nt*16 + d0);
    f4 o;
    #pragma unroll
    for (int i = 0; i < 4; ++i){
      float sc = g4[i]*rs;
      o[i] = fmaf(vf[nt][i], sc, fmaf(-mu, sc, b4[i]));
    }
    xt[nt] = pk4(o);
  }
}

// scores: frag-major K, max-free softmax with DEFERRED normalization --
// returns r = 1/sum; pt holds unnormalized exp(s) (e^s in [0.7,1.4], fp16-safe).
__device__ __forceinline__ float scoresT(const h4 qt[4], const _Float16* Kf,
                                         h4 pt[6], int lane){
  f4 s[6];
  #pragma unroll
  for (int st = 0; st < 6; ++st){
    const _Float16* kr = Kf + st*1024 + lane*8;
    h8 w0 = *(const h8*)(kr);
    h8 w1 = *(const h8*)(kr + 512);
    f4 cc = {0.f,0.f,0.f,0.f};
    cc = MFMA4(lo4(w0), qt[0], cc);
    cc = MFMA4(hi4(w0), qt[1], cc);
    cc = MFMA4(lo4(w1), qt[2], cc);
    cc = MFMA4(hi4(w1), qt[3], cc);
    s[st] = cc;
  }
  float sm = 0.f;
  #pragma unroll
  for (int st = 0; st < 6; ++st)
    #pragma unroll
    for (int i = 0; i < 4; ++i){ float e = __expf(s[st][i]); s[st][i] = e; sm += e; }
  sm = q_sum(sm);
  #pragma unroll
  for (int st = 0; st < 6; ++st) pt[st] = pk4(s[st]);
  return 1.f/sm;
}

// dual-tile attention + residual + LN (q-bias prescaled fp32 in ws)
__device__ __forceinline__ void attnT2(h4 xA[4], h4 xB[4],
        const _Float16* Kf, const _Float16* Vt,
        const _Float16* __restrict__ Wqt, const float* __restrict__ qb,
        const _Float16* __restrict__ Wot, const float* __restrict__ bo,
        const float* __restrict__ g_, const float* __restrict__ b_,
        int lane, int m, int q){
  const int d0 = 4*q;
  f4 cA[4], cB[4];
  mm64T2(Wqt, xA, xB, cA, cB, lane, qb, d0);
  h4 qA[4], qB[4];
  #pragma unroll
  for (int nt = 0; nt < 4; ++nt){ qA[nt] = pk4(cA[nt]); qB[nt] = pk4(cB[nt]); }
  h4 pA[6], pB[6];
  float rA_ = scoresT(qA, Kf, pA, lane);
  float rB_ = scoresT(qB, Kf, pB, lane);
  // Prefetch Wo A-frags (global latency hides under PV)
  h8 wo0[4], wo1[4];
  #pragma unroll
  for (int nt = 0; nt < 4; ++nt){
    const _Float16* ar = Wot + (nt*128 + lane)*8;
    wo0[nt] = *(const h8*)(ar);
    wo1[nt] = *(const h8*)(ar + 512);
  }
  // O^T = V^T @ P^T (unnormalized), r folded into output pack
  h4 otA[4], otB[4];
  #pragma unroll
  for (int nt = 0; nt < 4; ++nt){
    const _Float16* vr = Vt + (nt*16+m)*SVT + 4*q;
    f4 ca0 = {0.f,0.f,0.f,0.f}, cb0 = {0.f,0.f,0.f,0.f};
    f4 ca1 = {0.f,0.f,0.f,0.f}, cb1 = {0.f,0.f,0.f,0.f};
    #pragma unroll
    for (int st = 0; st < 3; ++st){
      h4 v = *(const h4*)(vr + st*16);
      ca0 = MFMA4(v, pA[st], ca0);
      cb0 = MFMA4(v, pB[st], cb0);
    }
    #pragma unroll
    for (int st = 3; st < 6; ++st){
      h4 v = *(const h4*)(vr + st*16);
      ca1 = MFMA4(v, pA[st], ca1);
      cb1 = MFMA4(v, pB[st], cb1);
    }
    otA[nt] = pk4((ca0 + ca1) * rA_);
    otB[nt] = pk4((cb0 + cb1) * rB_);
  }
  // O proj (bias C-init) + residual + LN
  f4 vfA[4], vfB[4];
  #pragma unroll
  for (int nt = 0; nt < 4; ++nt){
    f4 b4 = *(const f4*)(bo + nt*16 + d0);
    f4 ca = b4, cb = b4;
    ca = MFMA4(lo4(wo0[nt]), otA[0], ca);  cb = MFMA4(lo4(wo0[nt]), otB[0], cb);
    ca = MFMA4(hi4(wo0[nt]), otA[1], ca);  cb = MFMA4(hi4(wo0[nt]), otB[1], cb);
    ca = MFMA4(lo4(wo1[nt]), otA[2], ca);  cb = MFMA4(lo4(wo1[nt]), otB[2], cb);
    ca = MFMA4(hi4(wo1[nt]), otA[3], ca);  cb = MFMA4(hi4(wo1[nt]), otB[3], cb);
    #pragma unroll
    for (int i = 0; i < 4; ++i){
      vfA[nt][i] = ca[i] + (float)xA[nt][i];
      vfB[nt][i] = cb[i] + (float)xB[nt][i];
    }
  }
  lnT(vfA, xA, g_, b_, q);
  lnT(vfB, xB, g_, b_, q);
}

// single-tile attention (decoder)
__device__ __forceinline__ void attnT(h4 xt[4], const _Float16* Kf, const _Float16* Vt,
        const _Float16* __restrict__ Wqt, const float* __restrict__ qb,
        const _Float16* __restrict__ Wot, const float* __restrict__ bo,
        const float* __restrict__ g_, const float* __restrict__ b_,
        int lane, int m, int q){
  const int d0 = 4*q;
  f4 c[4];
  mm64T(Wqt, xt, c, lane, qb, d0);
  h4 qt[4];
  #pragma unroll
  for (int nt = 0; nt < 4; ++nt) qt[nt] = pk4(c[nt]);
  h4 pt[6];
  float r_ = scoresT(qt, Kf, pt, lane);
  h8 wo0[4], wo1[4];
  #pragma unroll
  for (int nt = 0; nt < 4; ++nt){
    const _Float16* ar = Wot + (nt*128 + lane)*8;
    wo0[nt] = *(const h8*)(ar);
    wo1[nt] = *(const h8*)(ar + 512);
  }
  h4 ot[4];
  #pragma unroll
  for (int nt = 0; nt < 4; ++nt){
    const _Float16* vr = Vt + (nt*16+m)*SVT + 4*q;
    f4 c0 = {0.f,0.f,0.f,0.f}, c1 = {0.f,0.f,0.f,0.f};
    #pragma unroll
    for (int st = 0; st < 3; ++st)
      c0 = MFMA4(*(const h4*)(vr + st*16), pt[st], c0);
    #pragma unroll
    for (int st = 3; st < 6; ++st)
      c1 = MFMA4(*(const h4*)(vr + st*16), pt[st], c1);
    ot[nt] = pk4((c0 + c1) * r_);
  }
  f4 vf[4];
  #pragma unroll
  for (int nt = 0; nt < 4; ++nt){
    f4 cc = *(const f4*)(bo + nt*16 + d0);
    cc = MFMA4(lo4(wo0[nt]), ot[0], cc);
    cc = MFMA4(hi4(wo0[nt]), ot[1], cc);
    cc = MFMA4(lo4(wo1[nt]), ot[2], cc);
    cc = MFMA4(hi4(wo1[nt]), ot[3], cc);
    #pragma unroll
    for (int i = 0; i < 4; ++i) vf[nt][i] = cc[i] + (float)xt[nt][i];
  }
  lnT(vf, xt, g_, b_, q);
}

// dual-tile FFN d->d + residual + LN (biases C-init)
__device__ __forceinline__ void ffnT2(h4 xA[4], h4 xB[4],
        const _Float16* __restrict__ W1t, const float* __restrict__ b1,
        const _Float16* __restrict__ W2t, const float* __restrict__ b2,
        const float* __restrict__ g_, const float* __restrict__ b_,
        int lane, int q){
  const int d0 = 4*q;
  f4 cA[4], cB[4];
  mm64T2(W1t, xA, xB, cA, cB, lane, b1, d0);
  h4 hA[4], hB[4];
  #pragma unroll
  for (int nt = 0; nt < 4; ++nt){ hA[nt] = relu_pk(cA[nt]); hB[nt] = relu_pk(cB[nt]); }
  f4 yA[4], yB[4];
  mm64T2(W2t, hA, hB, yA, yB, lane, b2, d0);
  f4 vfA[4], vfB[4];
  #pragma unroll
  for (int nt = 0; nt < 4; ++nt){
    #pragma unroll
    for (int i = 0; i < 4; ++i){
      vfA[nt][i] = yA[nt][i] + (float)xA[nt][i];
      vfB[nt][i] = yB[nt][i] + (float)xB[nt][i];
    }
  }
  lnT(vfA, xA, g_, b_, q);
  lnT(vfB, xB, g_, b_, q);
}

// dual-tile K/V build (biases C-init): K frag-major b128 stores; Vt scatter.
__device__ __forceinline__ void kvT2(const h4 xA[4], const h4 xB[4], int rA, int rB,
        _Float16* Kf, _Float16* Vt,
        const _Float16* __restrict__ Wkt, const float* __restrict__ bk,
        const _Float16* __restrict__ Wvt, const float* __restrict__ bv,
        int lane, int m, int q){
  const int d0 = 4*q;
  f4 cA[4], cB[4];
  mm64T2(Wkt, xA, xB, cA, cB, lane, bk, d0);
  {
    h4 oA[4], oB[4];
    #pragma unroll
    for (int nt = 0; nt < 4; ++nt){ oA[nt] = pk4(cA[nt]); oB[nt] = pk4(cB[nt]); }
    const int stA = rA >> 4, stB = rB >> 4;
    *(h8*)(Kf + stA*1024       + lane*8) = cat8(oA[0], oA[1]);
    *(h8*)(Kf + stA*1024 + 512 + lane*8) = cat8(oA[2], oA[3]);
    *(h8*)(Kf + stB*1024       + lane*8) = cat8(oB[0], oB[1]);
    *(h8*)(Kf + stB*1024 + 512 + lane*8) = cat8(oB[2], oB[3]);
  }
  mm64T2(Wvt, xA, xB, cA, cB, lane, bv, d0);
  #pragma unroll
  for (int nt = 0; nt < 4; ++nt){
    #pragma unroll
    for (int i = 0; i < 4; ++i){
      Vt[(nt*16 + d0 + i)*SVT + rA + m] = (_Float16)cA[nt][i];
      Vt[(nt*16 + d0 + i)*SVT + rB + m] = (_Float16)cB[nt][i];
    }
  }
}

// T-form conv (taps pre-mean-subtracted at callsite): 3 fma per element
__device__ __forceinline__ void convT(h4 xt[4], const float* __restrict__ cw,
                                      float xl, float xc, float xr, int q){
  const int d0 = 4*q;
  #pragma unroll
  for (int nt = 0; nt < 4; ++nt){
    const float* w = cw + 3*(nt*16 + d0);
    f4 o;
    #pragma unroll
    for (int i = 0; i < 4; ++i)
      o[i] = fmaf(w[3*i], xl, fmaf(w[3*i+1], xc, w[3*i+2]*xr));
    xt[nt] = pk4(o);
  }
}

// ---- weight prep: fp32 -> fp16 FRAG-MAJOR; Wq*0.125; prescaled fp32 q-biases ----
__global__ void prep_weights(Params p, _Float16* ws){
  const float* sq[10] = {p.eWq, p.eWk, p.eWv, p.eWo, p.ec1_w, p.ec2_w,
                         p.dWq, p.dWk, p.dWv, p.dWo};
  for (int idx = blockIdx.x*blockDim.x + threadIdx.x; idx < WS_TOTAL;
       idx += gridDim.x*blockDim.x){
    int r  = idx & 4095;
    int h  = r & 7, l = (r>>3) & 63, kt2 = (r>>9) & 1, nt = r>>10;
    int m  = l & 15, q = l >> 4;
    int orow = nt*16 + m;
    int kk   = kt2*32 + (h>>2)*16 + q*4 + (h&3);
    float v;
    if (idx < WS_DC1){
      int mi = idx >> 12;
      float sc = (mi == 0 || mi == 6) ? 0.125f : 1.f;
      v = sq[mi][kk*64 + orow] * sc;
    } else if (idx < WS_DC2){
      int cc = (idx - WS_DC1) >> 12;
      v = p.dc1_w[kk*256 + cc*64 + orow];
    } else {
      int cc = (idx - WS_DC2) >> 12;
      v = p.dc2_w[(cc*64 + kk)*64 + orow];
    }
    ws[idx] = (_Float16)v;
  }
  int t0 = blockIdx.x*blockDim.x + threadIdx.x;
  if (t0 < 128){
    float* qb = (float*)(ws + WS_BQ);
    qb[t0] = (t0 < 64 ? p.ebq[t0] : p.dbq[t0 - 64]) * 0.125f;
  }
}

// waves_per_eu(3,4): ~128-reg allocator budget (no-spill verified at 84 VGPR).
__global__ void __launch_bounds__(NTHR)
__attribute__((amdgpu_waves_per_eu(3, 4)))
GraphTransformer_90237262889124_kernel(Params p, const _Float16* __restrict__ ws)
{
  __shared__ __align__(16) _Float16 lds[LDS_HALVES];
  _Float16* Kf   = lds + K_OFF;
  _Float16* Vt   = lds + VT_OFF;
  float*    serE = (float*)(lds + MISC_OFF);
  float*    serD = serE + 96;
  float*    stat = serD + 144;

  const int tid = threadIdx.x, lane = tid & 63, wave = tid >> 6;
  const int m = lane & 15, q = lane >> 4;
  const int d0 = 4*q;
  const int b = blockIdx.x / NNODE, n = blockIdx.x % NNODE;

  const _Float16* eWq_t = ws + WSQ(0);
  const _Float16* eWk_t = ws + WSQ(1);
  const _Float16* eWv_t = ws + WSQ(2);
  const _Float16* eWo_t = ws + WSQ(3);
  const _Float16* ec1_t = ws + WSQ(4);
  const _Float16* ec2_t = ws + WSQ(5);
  const _Float16* dWq_t = ws + WSQ(6);
  const _Float16* dWk_t = ws + WSQ(7);
  const _Float16* dWv_t = ws + WSQ(8);
  const _Float16* dWo_t = ws + WSQ(9);
  const _Float16* dc1f  = ws + WS_DC1;
  const _Float16* dc2f  = ws + WS_DC2;
  const float* qbE = (const float*)(ws + WS_BQ);
  const float* qbD = qbE + 64;

  // ---- P0: series loads ----
  if (tid < LE) serE[tid] = p.x_enc[(b*LE + tid)*NNODE + n];
  if (tid >= 48) serD[tid - 48] = p.x_dec[(b*LD + (tid - 48))*NNODE + n];
  __syncthreads();                       // B1
  // ---- P1: means ----
  if (wave == 0){
    float v = serE[lane] + (lane < 32 ? serE[64 + lane] : 0.f);
    float s = wave_sum(v);
    if (lane == 0) stat[0] = s * (1.f/96.f);
  }
  if (wave == 1){
    float v = (lane < OUTL) ? serD[lane] : 0.f;
    float s = wave_sum(v);
    if (lane == 0) stat[1] = s * (1.f/48.f);
  }
  __syncthreads();                       // B2

  const int rA = wave * 16;              // enc tile A rows
  const int rB = (wave + 3) * 16;        // enc tile B rows
  h4 xA[4], xB[4];
  // ---- P2: enc conv (both tiles) + enc K/V ----
  {
    const float mu = stat[0];
    int lA = rA + m;
    int lmA = lA ? lA-1 : LE-1;
    int lpA = (lA == LE-1) ? 0 : lA+1;
    convT(xA, p.enc_conv_w, serE[lmA]-mu, serE[lA]-mu, serE[lpA]-mu, q);
    int lB = rB + m;
    int lmB = lB - 1;                    // rB >= 48, never wraps low
    int lpB = (lB == LE-1) ? 0 : lB+1;
    convT(xB, p.enc_conv_w, serE[lmB]-mu, serE[lB]-mu, serE[lpB]-mu, q);
    kvT2(xA, xB, rA, rB, Kf, Vt, eWk_t, p.ebk, eWv_t, p.ebv, lane, m, q);
  }
  __syncthreads();                       // B3: enc K/V visible
  // ---- P3: enc attention + FFN (dual-tile) ----
  attnT2(xA, xB, Kf, Vt, eWq_t, qbE, eWo_t, p.ebo, p.en1_g, p.en1_b, lane, m, q);
  ffnT2(xA, xB, ec1_t, p.ec1_b, ec2_t, p.ec2_b, p.en2_g, p.en2_b, lane, q);
  __syncthreads();                       // B4: all attn reads done
  // ---- P4: dec cross K/V from enc_out; dec conv hoisted ----
  h4 xt[4];
  {
    const float mu = stat[1];
    const int gr = 96 + rA + m;
    float xl = serD[gr-1];
    float xc = serD[gr];
    float xr = (gr == LD-1) ? (serD[0] - mu) : serD[gr+1];
    convT(xt, p.dec_conv_w, xl, xc, xr, q);
  }
  kvT2(xA, xB, rA, rB, Kf, Vt, dWk_t, p.dbk, dWv_t, p.dbv, lane, m, q);
  __syncthreads();                       // B5: dec K/V visible
  // ---- P5: decoder (all 3 waves, one tile each) ----
  {
    attnT(xt, Kf, Vt, dWq_t, qbD, dWo_t, p.dbo, p.dn2_g, p.dn2_b, lane, m, q);
    // FFN d->4d->d, 4 hidden chunks; acc C-init with dc2_b (bias once)
    f4 acc[4];
    #pragma unroll
    for (int nt = 0; nt < 4; ++nt) acc[nt] = *(const f4*)(p.dc2_b + nt*16 + d0);
    for (int cc2 = 0; cc2 < 4; ++cc2){
      f4 hh[4];
      mm64T(dc1f + cc2*4096, xt, hh, lane, p.dc1_b + cc2*64, d0);
      h4 ht[4];
      #pragma unroll
      for (int nt = 0; nt < 4; ++nt) ht[nt] = relu_pk(hh[nt]);
      #pragma unroll
      for (int nt = 0; nt < 4; ++nt){
        const _Float16* ar = dc2f + cc2*4096 + (nt*128 + lane)*8;
        h8 w0 = *(const h8*)(ar);
        h8 w1 = *(const h8*)(ar + 512);
        acc[nt] = MFMA4(lo4(w0), ht[0], acc[nt]);
        acc[nt] = MFMA4(hi4(w0), ht[1], acc[nt]);
        acc[nt] = MFMA4(lo4(w1), ht[2], acc[nt]);
        acc[nt] = MFMA4(hi4(w1), ht[3], acc[nt]);
      }
    }
    // final LN(dn3) + proj + enc-mean
    f4 vf[4];
    #pragma unroll
    for (int nt = 0; nt < 4; ++nt){
      #pragma unroll
      for (int i = 0; i < 4; ++i) vf[nt][i] = acc[nt][i] + (float)xt[nt][i];
    }
    float s = 0.f, s2 = 0.f;
    #pragma unroll
    for (int nt = 0; nt < 4; ++nt)
      #pragma unroll
      for (int i = 0; i < 4; ++i){ float v = vf[nt][i]; s += v; s2 = fmaf(v, v, s2); }
    s = q_sum(s); s2 = q_sum(s2);
    float mu = s * (1.f/64.f);
    float rs = rsqrtf(fmaxf(s2 * (1.f/64.f) - mu*mu, 0.f) + 1e-5f);
    float pp = 0.f;
    #pragma unroll
    for (int nt = 0; nt < 4; ++nt){
      f4 g4 = *(const f4*)(p.dn3_g + nt*16 + d0);
      f4 b4 = *(const f4*)(p.dn3_b + nt*16 + d0);
      f4 w4 = *(const f4*)(p.proj_w + nt*16 + d0);
      #pragma unroll
      for (int i = 0; i < 4; ++i)
        pp += ((vf[nt][i]-mu)*rs*g4[i] + b4[i]) * w4[i];
    }
    pp = q_sum(pp);
    if (q == 0)
      p.out[(b*OUTL + rA + m)*NNODE + n] = pp + p.proj_b[0] + stat[0];
  }
}

extern "C" void kernel_launch(void* const* d_in, const int* in_sizes, int n_in,
                              void* d_out, int out_size, void* d_ws, size_t ws_size,
                              hipStream_t stream) {
  Params p;
  p.x_enc = (const float*)d_in[0];  p.x_dec = (const float*)d_in[1];
  p.enc_conv_w = (const float*)d_in[4];  p.dec_conv_w = (const float*)d_in[5];
  p.eWq = (const float*)d_in[6];   p.ebq = (const float*)d_in[7];
  p.eWk = (const float*)d_in[8];   p.ebk = (const float*)d_in[9];
  p.eWv = (const float*)d_in[10];  p.ebv = (const float*)d_in[11];
  p.eWo = (const float*)d_in[12];  p.ebo = (const float*)d_in[13];
  p.ec1_w = (const float*)d_in[14]; p.ec1_b = (const float*)d_in[15];
  p.ec2_w = (const float*)d_in[16]; p.ec2_b = (const float*)d_in[17];
  p.en1_g = (const float*)d_in[18]; p.en1_b = (const float*)d_in[19];
  p.en2_g = (const float*)d_in[20]; p.en2_b = (const float*)d_in[21];
  p.dWq = (const float*)d_in[22];  p.dbq = (const float*)d_in[23];
  p.dWk = (const float*)d_in[24];  p.dbk = (const float*)d_in[25];
  p.dWv = (const float*)d_in[26];  p.dbv = (const float*)d_in[27];
  p.dWo = (const float*)d_in[28];  p.dbo = (const float*)d_in[29];
  p.dc1_w = (const float*)d_in[30]; p.dc1_b = (const float*)d_in[31];
  p.dc2_w = (const float*)d_in[32]; p.dc2_b = (const float*)d_in[33];
  p.dn2_g = (const float*)d_in[34]; p.dn2_b = (const float*)d_in[35];
  p.dn3_g = (const float*)d_in[36]; p.dn3_b = (const float*)d_in[37];
  p.proj_w = (const float*)d_in[38]; p.proj_b = (const float*)d_in[39];
  p.out = (float*)d_out;

  _Float16* ws = (_Float16*)d_ws;
  prep_weights<<<144, 512, 0, stream>>>(p, ws);
  GraphTransformer_90237262889124_kernel<<<NSEQ, NTHR, 0, stream>>>(p, ws);
}